// Round 5
// baseline (13542.154 us; speedup 1.0000x reference)
//
#include <hip/hip_runtime.h>

typedef unsigned short ushort_t;
typedef unsigned int uint_t;
typedef unsigned long long u64;
typedef __attribute__((ext_vector_type(8))) short short8;
typedef __attribute__((ext_vector_type(4))) float floatx4;
typedef __attribute__((ext_vector_type(4))) uint_t uintx4;

#define S_LEN 1024
#define BATCH 32
#define HDIM  256
#define GDIM  1024  /* 4H */
#define DIN   128

__device__ __forceinline__ float bf2f(ushort_t u) { return __uint_as_float(((unsigned)u) << 16); }
__device__ __forceinline__ float bf2fs(short s)   { return __uint_as_float(((unsigned)(unsigned short)s) << 16); }
__device__ __forceinline__ ushort_t f2bf(float f) {
  unsigned u = __float_as_uint(f);
  unsigned r = (u + 0x7fffu + ((u >> 16) & 1u)) >> 16;
  return (ushort_t)r;
}
__device__ __forceinline__ float sigf(float x) { return 1.f / (1.f + __expf(-x)); }
__device__ __forceinline__ float tanh_f(float x) {
  float ax = fabsf(x);
  float e = __expf(2.f * ax);
  float r = 1.f - 2.f / (e + 1.f);
  return x < 0.f ? -r : r;
}

__device__ __forceinline__ void load_lds16(const void* g, void* l) {
  __builtin_amdgcn_global_load_lds((const __attribute__((address_space(1))) unsigned int*)g,
                                   (__attribute__((address_space(3))) unsigned int*)l, 16, 0, 0);
}

// LDS-only barrier: drains lgkm but NOT vmcnt (in-flight global prefetches and
// fire-and-forget stores stay in flight). sched_barrier fences per rule #18.
__device__ __forceinline__ void lds_barrier() {
  __builtin_amdgcn_sched_barrier(0);
  asm volatile("s_waitcnt lgkmcnt(0)" ::: "memory");
  __builtin_amdgcn_s_barrier();
  __builtin_amdgcn_sched_barrier(0);
}

// ---------------------------------------------------------------------------
// Generic bf16 MFMA GEMM: C[m][n] = sum_k A[m][k]*B[n][k] + bias[n]
// mode 0: bf16 at C[m*N+n]          (h layout [t][b][n], m = t*32+b)
// mode 1: fp32 at out[b][t][n]      (head output)
// mode 2: bf16 at C[t][n][b]        (xp transposed for vectorized recurrence)
// ---------------------------------------------------------------------------
__global__ __launch_bounds__(256) void gemm_bf16(
    const ushort_t* __restrict__ A, const ushort_t* __restrict__ Bw,
    const float* __restrict__ bias, void* __restrict__ Cout,
    int M, int N, int K, int mode)
{
  __shared__ __align__(16) ushort_t As[128 * 64];
  __shared__ __align__(16) ushort_t Bs[128 * 64];
  const int tid = threadIdx.x;
  const int lane = tid & 63, wid = tid >> 6;
  const int wm = wid >> 1, wn = wid & 1;
  const int bm = blockIdx.y, bn = blockIdx.x;
  const int l15 = lane & 15, q4 = lane >> 4;

  const int r  = tid >> 3;
  const int c8 = tid & 7;
  const int g8 = c8 ^ (r & 7);

  floatx4 zero4 = {0.f, 0.f, 0.f, 0.f};
  floatx4 acc[4][4];
#pragma unroll
  for (int mt = 0; mt < 4; ++mt)
#pragma unroll
    for (int nt = 0; nt < 4; ++nt) acc[mt][nt] = zero4;

  for (int k0 = 0; k0 < K; k0 += 64) {
    __syncthreads();
#pragma unroll
    for (int p = 0; p < 4; ++p) {
      int row = p * 32 + r;
      load_lds16(A + (size_t)(bm * 128 + row) * K + k0 + g8 * 8, (void*)(As + p * 2048 + wid * 512));
      load_lds16(Bw + (size_t)(bn * 128 + row) * K + k0 + g8 * 8, (void*)(Bs + p * 2048 + wid * 512));
    }
    __syncthreads();
#pragma unroll
    for (int ks = 0; ks < 2; ++ks) {
      const int kk = ks * 4 + q4;
      short8 af[4], bf[4];
#pragma unroll
      for (int mt = 0; mt < 4; ++mt) {
        int row = wm * 64 + mt * 16 + l15;
        af[mt] = *(const short8*)(As + row * 64 + ((kk ^ (row & 7)) << 3));
      }
#pragma unroll
      for (int nt = 0; nt < 4; ++nt) {
        int row = wn * 64 + nt * 16 + l15;
        bf[nt] = *(const short8*)(Bs + row * 64 + ((kk ^ (row & 7)) << 3));
      }
#pragma unroll
      for (int mt = 0; mt < 4; ++mt)
#pragma unroll
        for (int nt = 0; nt < 4; ++nt)
          acc[mt][nt] = __builtin_amdgcn_mfma_f32_16x16x32_bf16(af[mt], bf[nt], acc[mt][nt], 0, 0, 0);
    }
  }

#pragma unroll
  for (int mt = 0; mt < 4; ++mt)
#pragma unroll
    for (int nt = 0; nt < 4; ++nt)
#pragma unroll
      for (int rr = 0; rr < 4; ++rr) {
        int m = bm * 128 + wm * 64 + mt * 16 + q4 * 4 + rr;
        int n = bn * 128 + wn * 64 + nt * 16 + l15;
        float v = acc[mt][nt][rr] + bias[n];
        if (mode == 0) {
          ((ushort_t*)Cout)[(size_t)m * N + n] = f2bf(v);
        } else if (mode == 1) {
          int t = m >> 5, b = m & 31;
          ((float*)Cout)[(size_t)b * (S_LEN * DIN) + t * DIN + n] = v;
        } else {
          int t = m >> 5, b = m & 31;
          ((ushort_t*)Cout)[(size_t)t * (N * 32) + n * 32 + b] = f2bf(v);
        }
      }
}

// ---------------------------------------------------------------------------
// Bidirectional LSTM recurrence — 2 WGs per direction, tagged-word exchange.
// Grid = 4 WGs x 512 threads: dir = bx&1, half = bx>>1 (128-col h half).
//
// Topology: each WG owns ALL FOUR gates for its 128 h-cols (wave w owns gate
// rows {gg*256 + half*128 + w*16 + l | gg in 0..3, l in 0..15}), so the MFMA
// C-layout (col=lane&15, row=(lane>>4)*4+rr) delivers i,f,g,o for a given
// (batch,col) into the SAME lane -> the cell is register-local: no stage
// array, no second-phase cross-wave shuffle. Exchange partner count = 1
// (the other half), eliminating R4's max-of-7 producer straggler term.
//
// Protocol: tagged words, drain-free. Each exchanged u32 = (bf16 h)<<16 | sc
// tag; u32 accesses are single-copy atomic, so ANY mix of old/new words is
// detected per-word with zero ordering assumptions. Producer publishes with
// no vmcnt drain, no barrier, no epoch. Consumer spins on 4B ONLY (R1's
// failure was 128B bulk-spin traffic; R2's was a dishonest pre-drain epoch
// that degenerated into bulk retries), then one 32B load + per-word
// validate/retry (rare: the 32B comes from one producer wave-store burst).
//
// Overwrite safety (parity-2 double buffer, same induction as R0/R4):
// my publish(sc+1) overwrites parity data of step sc-1; partner consumed
// that during its step sc-1, and I publish sc+1 only after my consume of
// partner's sc succeeded; partner stored sc only after its consume(sc-1)
// loads completed (validate uses the loaded values -> loads complete before
// the program-ordered publish). Graph-replay safe: comm zeroed per launch
// (tag 0 never equals a live tag 1..1024).
// ---------------------------------------------------------------------------
__global__ __launch_bounds__(512, 2) void lstm_layer(
    const ushort_t* __restrict__ xpf, const ushort_t* __restrict__ xpb,
    const ushort_t* __restrict__ whhf, const ushort_t* __restrict__ whhb,
    ushort_t* __restrict__ hout, uint_t* __restrict__ comm)
{
  const int bx = blockIdx.x;
  const int dir = bx & 1, half = bx >> 1;

  const ushort_t* xp  = dir ? xpb : xpf;
  const ushort_t* whh = dir ? whhb : whhf;
  uint_t* commd = comm + (size_t)dir * 16384;  // 2 parities x [32 batch][256 col] u32
  const int hoff = dir * 256;
  const int choff = half * 128;

  __shared__ __align__(16) ushort_t hbuf[32 * 264];  // h_{t-1} bf16 [batch][256 cols], stride 264

  const int tid = threadIdx.x, lane = tid & 63, w = tid >> 6;  // w in 0..7
  const int l15 = lane & 15, q4 = lane >> 4;

  // permanent B-fragments: wave w owns gate rows gg*256 + choff + w*16 + l15
  short8 Bf[4][8];
#pragma unroll
  for (int gg = 0; gg < 4; ++gg) {
    int grow = gg * 256 + choff + w * 16 + l15;
#pragma unroll
    for (int ks = 0; ks < 8; ++ks)
      Bf[gg][ks] = *(const short8*)(whh + (size_t)grow * 256 + ks * 32 + q4 * 8);
  }

  // zero hbuf: h_{-1} = 0 (sc==0 skips the consume phase)
  for (int i = tid; i < 32 * 132; i += 512) ((uint_t*)hbuf)[i] = 0u;

  float cst[2][4];
#pragma unroll
  for (int mt = 0; mt < 2; ++mt)
#pragma unroll
    for (int rr = 0; rr < 4; ++rr) cst[mt][rr] = 0.f;

  // xp prefetch: [t][g][b] layout, one u64 = 4 consecutive batches
  u64 xr64[4][2];
  auto ldxp = [&](int tt) {
#pragma unroll
    for (int gg = 0; gg < 4; ++gg)
#pragma unroll
      for (int mt = 0; mt < 2; ++mt) {
        int g = gg * 256 + choff + w * 16 + l15;
        xr64[gg][mt] = *(const u64*)(xp + (size_t)tt * (GDIM * BATCH) + (size_t)g * 32 + mt * 16 + q4 * 4);
      }
  };

  // exchange thread mapping: (batch cb2, 8-col chunk ch)
  const int cb2 = tid >> 4;            // 0..31
  const int ch  = tid & 15;            // 0..15
  const int obase = choff + ch * 8;          // own cols published
  const int rbase = (128 - choff) + ch * 8;  // remote cols consumed

  ldxp((dir == 0) ? 0 : 1023);
  __syncthreads();

  for (int sc = 0; sc < 1024; ++sc) {
    const int tcur  = (dir == 0) ? sc : 1023 - sc;
    const int tnext = (dir == 0) ? (sc < 1023 ? sc + 1 : 1023) : (sc < 1023 ? 1022 - sc : 0);

    // unpack previous prefetch into acc (gates init = xp)
    floatx4 acc[4][2];
#pragma unroll
    for (int gg = 0; gg < 4; ++gg)
#pragma unroll
      for (int mt = 0; mt < 2; ++mt) {
        u64 v = xr64[gg][mt];
#pragma unroll
        for (int rr = 0; rr < 4; ++rr)
          acc[gg][mt][rr] = bf2f((ushort_t)(v >> (16 * rr)));
      }

    ldxp(tnext);  // next step's xp; stays in flight across lgkm barriers

    // ---- consume partner half: 4B spin -> 32B load -> per-word validate ----
    if (sc > 0) {
      const uint_t want = (uint_t)sc;
      const uint_t* rb = commd + (size_t)(sc & 1) * 8192 + cb2 * 256 + rbase;
      while ((__hip_atomic_load(rb, __ATOMIC_RELAXED, __HIP_MEMORY_SCOPE_AGENT) & 0xffffu) != want) { }
      const u64* rb64 = (const u64*)rb;
      u64 wv[4];
#pragma unroll
      for (int k = 0; k < 4; ++k)
        wv[k] = __hip_atomic_load(rb64 + k, __ATOMIC_RELAXED, __HIP_MEMORY_SCOPE_AGENT);
#pragma unroll
      for (int k = 0; k < 4; ++k) {
        while ((((uint_t)wv[k] & 0xffffu) != want) | (((uint_t)(wv[k] >> 32) & 0xffffu) != want))
          wv[k] = __hip_atomic_load(rb64 + k, __ATOMIC_RELAXED, __HIP_MEMORY_SCOPE_AGENT);
      }
      // unpack 8 cols -> hbuf[cb2][rbase..rbase+8)
      uint_t p[4];
#pragma unroll
      for (int k = 0; k < 4; ++k) {
        uint_t c0 = (uint_t)(wv[k] >> 16) & 0xffffu;
        uint_t c1 = (uint_t)(wv[k] >> 48);
        p[k] = c0 | (c1 << 16);
      }
      *(u64*)(hbuf + cb2 * 264 + rbase)     = (u64)p[0] | ((u64)p[1] << 32);
      *(u64*)(hbuf + cb2 * 264 + rbase + 4) = (u64)p[2] | ((u64)p[3] << 32);
    }
    lds_barrier();  // hbuf ready (own half written before prev step's barrier)

    // ---- gates += h_{t-1} @ whh^T via MFMA (A = h batches, B = gate rows) ----
#pragma unroll
    for (int ks = 0; ks < 8; ++ks) {
      short8 a0 = *(const short8*)(hbuf + l15 * 264 + ks * 32 + q4 * 8);
      short8 a1 = *(const short8*)(hbuf + (16 + l15) * 264 + ks * 32 + q4 * 8);
#pragma unroll
      for (int gg = 0; gg < 4; ++gg) {
        acc[gg][0] = __builtin_amdgcn_mfma_f32_16x16x32_bf16(a0, Bf[gg][ks], acc[gg][0], 0, 0, 0);
        acc[gg][1] = __builtin_amdgcn_mfma_f32_16x16x32_bf16(a1, Bf[gg][ks], acc[gg][1], 0, 0, 0);
      }
    }

    // ---- register-local LSTM cell: lane owns (col = choff+w*16+l15,
    //      batches mt*16+q4*4+rr); i,f,g,o all in this lane's acc ----
#pragma unroll
    for (int mt = 0; mt < 2; ++mt)
#pragma unroll
      for (int rr = 0; rr < 4; ++rr) {
        float gi = acc[0][mt][rr];
        float gf = acc[1][mt][rr];
        float gz = acc[2][mt][rr];
        float go = acc[3][mt][rr];
        float c = sigf(gf) * cst[mt][rr] + sigf(gi) * tanh_f(gz);
        cst[mt][rr] = c;
        float hv = sigf(go) * tanh_f(c);
        // scatter own h into hbuf[batch][col] (2-way banked u16 writes)
        hbuf[(mt * 16 + q4 * 4 + rr) * 264 + choff + w * 16 + l15] = f2bf(hv);
      }
    lds_barrier();  // own-half h visible for transpose-publish + next MFMA

    // ---- transpose-publish: coalesced 16B read -> tagged stores (no drain,
    //      no barrier, no epoch). hout off the critical path. ----
    {
      uintx4 hv = *(const uintx4*)(hbuf + cb2 * 264 + obase);  // 8 own cols
      const uint_t tag = (uint_t)(sc + 1);
      u64* cd = (u64*)(commd + (size_t)((sc + 1) & 1) * 8192 + cb2 * 256 + obase);
      uint_t t0, t1;
      t0 = ((hv.x & 0xffffu) << 16) | tag;  t1 = (hv.x & 0xffff0000u) | tag;
      __hip_atomic_store(cd + 0, (u64)t0 | ((u64)t1 << 32), __ATOMIC_RELAXED, __HIP_MEMORY_SCOPE_AGENT);
      t0 = ((hv.y & 0xffffu) << 16) | tag;  t1 = (hv.y & 0xffff0000u) | tag;
      __hip_atomic_store(cd + 1, (u64)t0 | ((u64)t1 << 32), __ATOMIC_RELAXED, __HIP_MEMORY_SCOPE_AGENT);
      t0 = ((hv.z & 0xffffu) << 16) | tag;  t1 = (hv.z & 0xffff0000u) | tag;
      __hip_atomic_store(cd + 2, (u64)t0 | ((u64)t1 << 32), __ATOMIC_RELAXED, __HIP_MEMORY_SCOPE_AGENT);
      t0 = ((hv.w & 0xffffu) << 16) | tag;  t1 = (hv.w & 0xffff0000u) | tag;
      __hip_atomic_store(cd + 3, (u64)t0 | ((u64)t1 << 32), __ATOMIC_RELAXED, __HIP_MEMORY_SCOPE_AGENT);

      *(uintx4*)(hout + (size_t)tcur * (BATCH * 512) + cb2 * 512 + hoff + obase) = hv;
    }
    // no end-of-step barrier: next step's consume writes the REMOTE half of
    // hbuf (disjoint from this step's own-half reads), and the post-consume
    // lds_barrier orders everything before the next MFMA.
  }
}

// ---------------------------------------------------------------------------
// Attention scores -> e = exp(s - max_t s), per batch b.
// ---------------------------------------------------------------------------
__global__ __launch_bounds__(256) void attn_scores(
    const ushort_t* __restrict__ h1, const float* __restrict__ attn_w,
    const float* __restrict__ attn_b, float* __restrict__ e_out)
{
  const int b = blockIdx.x;
  __shared__ float sbuf[1024];
  __shared__ float red[4];
  const int tid = threadIdx.x, lane = tid & 63, w = tid >> 6;

  float wreg[8];
#pragma unroll
  for (int i = 0; i < 8; ++i) wreg[i] = attn_w[lane * 8 + i];

  for (int t = w; t < 1024; t += 4) {
    short8 hv = *(const short8*)(h1 + (size_t)t * (BATCH * 512) + b * 512 + lane * 8);
    float dot = 0.f;
#pragma unroll
    for (int i = 0; i < 8; ++i) dot += bf2fs(hv[i]) * wreg[i];
#pragma unroll
    for (int off = 32; off; off >>= 1) dot += __shfl_xor(dot, off);
    if (lane == 0) sbuf[t] = dot + attn_b[0];
  }
  __syncthreads();
  float m = -1e30f;
  for (int t = tid; t < 1024; t += 256) m = fmaxf(m, sbuf[t]);
#pragma unroll
  for (int off = 32; off; off >>= 1) m = fmaxf(m, __shfl_xor(m, off));
  if (lane == 0) red[w] = m;
  __syncthreads();
  float mm = fmaxf(fmaxf(red[0], red[1]), fmaxf(red[2], red[3]));
  for (int t = tid; t < 1024; t += 256) e_out[b * 1024 + t] = __expf(sbuf[t] - mm);
}

// ---------------------------------------------------------------------------
// Cumulative context: ctx[t][b][c] = (sum_{u<=t} e_u h_u[c]) / (sum e_u), bf16.
// ---------------------------------------------------------------------------
__global__ __launch_bounds__(256) void attn_ctx(
    const ushort_t* __restrict__ h1, const float* __restrict__ e_in, ushort_t* __restrict__ ctx)
{
  const int b = blockIdx.x >> 1, half = blockIdx.x & 1;
  const int c = half * 256 + threadIdx.x;
  float num = 0.f, den = 0.f;
  const ushort_t* hp = h1 + b * 512 + c;
  ushort_t* cp = ctx + b * 512 + c;
  const float* ep = e_in + b * 1024;
#pragma unroll 4
  for (int t = 0; t < 1024; ++t) {
    float ev = ep[t];
    float hv = bf2f(hp[(size_t)t * (BATCH * 512)]);
    num += ev * hv;
    den += ev;
    cp[(size_t)t * (BATCH * 512)] = f2bf(num / den);
  }
}

// ---------------------------------------------------------------------------
// casts
// ---------------------------------------------------------------------------
__global__ void castw(const float* __restrict__ in, ushort_t* __restrict__ out, int n) {
  int i = blockIdx.x * 256 + threadIdx.x;
  if (i < n) out[i] = f2bf(in[i]);
}
__global__ void castx(const float* __restrict__ x, ushort_t* __restrict__ xt) {
  int i = blockIdx.x * 256 + threadIdx.x;  // over 32768*128
  int dcol = i & 127;
  int m = i >> 7;
  int b = m & 31, s = m >> 5;
  xt[i] = f2bf(x[(size_t)b * (S_LEN * DIN) + s * DIN + dcol]);
}

extern "C" void kernel_launch(void* const* d_in, const int* in_sizes, int n_in,
                              void* d_out, int out_size, void* d_ws, size_t ws_size,
                              hipStream_t stream)
{
  const float* x     = (const float*)d_in[0];
  const float* wih0f = (const float*)d_in[1];
  const float* whh0f = (const float*)d_in[2];
  const float* b0f   = (const float*)d_in[3];
  const float* wih0b = (const float*)d_in[4];
  const float* whh0b = (const float*)d_in[5];
  const float* b0b   = (const float*)d_in[6];
  const float* wih1f = (const float*)d_in[7];
  const float* whh1f = (const float*)d_in[8];
  const float* b1f   = (const float*)d_in[9];
  const float* wih1b = (const float*)d_in[10];
  const float* whh1b = (const float*)d_in[11];
  const float* b1b   = (const float*)d_in[12];
  const float* attw  = (const float*)d_in[13];
  const float* attb  = (const float*)d_in[14];
  const float* headw = (const float*)d_in[15];
  const float* headb = (const float*)d_in[16];
  float* out = (float*)d_out;

  char* p = (char*)d_ws;
  auto alloc = [&](size_t bytes) {
    char* r = p;
    p += (bytes + 511) & ~(size_t)511;
    return r;
  };
  uint_t* comm0   = (uint_t*)alloc(32768 * 4); // layer-0: 2dir x 2par x 32b x 256col tagged u32 (128KB)
  uint_t* comm1   = (uint_t*)alloc(32768 * 4); // layer-1 (contiguous: one memset)
  ushort_t* xt    = (ushort_t*)alloc((size_t)32768 * 128 * 2);
  ushort_t* cwih0f = (ushort_t*)alloc(131072 * 2);
  ushort_t* cwih0b = (ushort_t*)alloc(131072 * 2);
  ushort_t* cwhh0f = (ushort_t*)alloc(262144 * 2);
  ushort_t* cwhh0b = (ushort_t*)alloc(262144 * 2);
  ushort_t* cwih1f = (ushort_t*)alloc(524288 * 2);
  ushort_t* cwih1b = (ushort_t*)alloc(524288 * 2);
  ushort_t* cwhh1f = (ushort_t*)alloc(262144 * 2);
  ushort_t* cwhh1b = (ushort_t*)alloc(262144 * 2);
  ushort_t* cwhead = (ushort_t*)alloc(65536 * 2);
  ushort_t* xpA = (ushort_t*)alloc((size_t)32768 * 1024 * 2);
  ushort_t* xpB = (ushort_t*)alloc((size_t)32768 * 1024 * 2);
  ushort_t* h0  = (ushort_t*)alloc((size_t)32768 * 512 * 2);
  ushort_t* h1  = (ushort_t*)alloc((size_t)32768 * 512 * 2);
  float* ebuf   = (float*)alloc(32 * 1024 * 4);
  ushort_t* ctx = xpA;  // reuse (xp dead by then)

  (void)in_sizes; (void)n_in; (void)out_size; (void)ws_size;

  // zero both layers' tagged comm (graph-replay safety: tag 0 != any sc+1 >= 1)
  (void)hipMemsetAsync(comm0, 0, 2 * 32768 * 4, stream);

  castw<<<512, 256, 0, stream>>>(wih0f, cwih0f, 131072);
  castw<<<512, 256, 0, stream>>>(wih0b, cwih0b, 131072);
  castw<<<1024, 256, 0, stream>>>(whh0f, cwhh0f, 262144);
  castw<<<1024, 256, 0, stream>>>(whh0b, cwhh0b, 262144);
  castw<<<2048, 256, 0, stream>>>(wih1f, cwih1f, 524288);
  castw<<<2048, 256, 0, stream>>>(wih1b, cwih1b, 524288);
  castw<<<1024, 256, 0, stream>>>(whh1f, cwhh1f, 262144);
  castw<<<1024, 256, 0, stream>>>(whh1b, cwhh1b, 262144);
  castw<<<256, 256, 0, stream>>>(headw, cwhead, 65536);
  castx<<<16384, 256, 0, stream>>>(x, xt);

  // layer 0: xp in transposed [t][g][b] layout (mode 2)
  gemm_bf16<<<dim3(8, 256), 256, 0, stream>>>(xt, cwih0f, b0f, xpA, 32768, 1024, 128, 2);
  gemm_bf16<<<dim3(8, 256), 256, 0, stream>>>(xt, cwih0b, b0b, xpB, 32768, 1024, 128, 2);
  lstm_layer<<<4, 512, 0, stream>>>(xpA, xpB, cwhh0f, cwhh0b, h0, comm0);

  // layer 1
  gemm_bf16<<<dim3(8, 256), 256, 0, stream>>>(h0, cwih1f, b1f, xpA, 32768, 1024, 512, 2);
  gemm_bf16<<<dim3(8, 256), 256, 0, stream>>>(h0, cwih1b, b1b, xpB, 32768, 1024, 512, 2);
  lstm_layer<<<4, 512, 0, stream>>>(xpA, xpB, cwhh1f, cwhh1b, h1, comm1);

  // attention + head
  attn_scores<<<32, 256, 0, stream>>>(h1, attw, attb, ebuf);
  attn_ctx<<<64, 256, 0, stream>>>(h1, ebuf, ctx);
  gemm_bf16<<<dim3(1, 256), 256, 0, stream>>>(ctx, cwhead, headb, out, 32768, 128, 512, 1);
}

// Round 6
// 7484.745 us; speedup vs baseline: 1.8093x; 1.8093x over previous
//
#include <hip/hip_runtime.h>

typedef unsigned short ushort_t;
typedef unsigned int uint_t;
typedef unsigned long long u64;
typedef __attribute__((ext_vector_type(8))) short short8;
typedef __attribute__((ext_vector_type(4))) float floatx4;

#define S_LEN 1024
#define BATCH 32
#define HDIM  256
#define GDIM  1024  /* 4H */
#define DIN   128

__device__ __forceinline__ float bf2f(ushort_t u) { return __uint_as_float(((unsigned)u) << 16); }
__device__ __forceinline__ float bf2fs(short s)   { return __uint_as_float(((unsigned)(unsigned short)s) << 16); }
__device__ __forceinline__ ushort_t f2bf(float f) {
  unsigned u = __float_as_uint(f);
  unsigned r = (u + 0x7fffu + ((u >> 16) & 1u)) >> 16;
  return (ushort_t)r;
}
__device__ __forceinline__ float sigf(float x) { return 1.f / (1.f + __expf(-x)); }
__device__ __forceinline__ float tanh_f(float x) {
  float ax = fabsf(x);
  float e = __expf(2.f * ax);
  float r = 1.f - 2.f / (e + 1.f);
  return x < 0.f ? -r : r;
}

__device__ __forceinline__ void load_lds16(const void* g, void* l) {
  __builtin_amdgcn_global_load_lds((const __attribute__((address_space(1))) unsigned int*)g,
                                   (__attribute__((address_space(3))) unsigned int*)l, 16, 0, 0);
}
__device__ __forceinline__ void vm0() { asm volatile("s_waitcnt vmcnt(0)" ::: "memory"); }

// LDS-only barrier: drains lgkm (LDS ops) but NOT vmcnt, so in-flight global
// prefetches and store-acks are NOT serialized here. sched_barrier fences
// prevent hipcc from hoisting LDS ops across (rule #18).
__device__ __forceinline__ void lds_barrier() {
  __builtin_amdgcn_sched_barrier(0);
  asm volatile("s_waitcnt lgkmcnt(0)" ::: "memory");
  __builtin_amdgcn_s_barrier();
  __builtin_amdgcn_sched_barrier(0);
}

// ---------------------------------------------------------------------------
// Generic bf16 MFMA GEMM: C[m][n] = sum_k A[m][k]*B[n][k] + bias[n]
// mode 0: bf16 at C[m*N+n]          (h layout [t][b][n], m = t*32+b)
// mode 1: fp32 at out[b][t][n]      (head output)
// mode 2: bf16 at C[t][n][b]        (xp transposed for vectorized recurrence)
// ---------------------------------------------------------------------------
__global__ __launch_bounds__(256) void gemm_bf16(
    const ushort_t* __restrict__ A, const ushort_t* __restrict__ Bw,
    const float* __restrict__ bias, void* __restrict__ Cout,
    int M, int N, int K, int mode)
{
  __shared__ __align__(16) ushort_t As[128 * 64];
  __shared__ __align__(16) ushort_t Bs[128 * 64];
  const int tid = threadIdx.x;
  const int lane = tid & 63, wid = tid >> 6;
  const int wm = wid >> 1, wn = wid & 1;
  const int bm = blockIdx.y, bn = blockIdx.x;
  const int l15 = lane & 15, q4 = lane >> 4;

  const int r  = tid >> 3;
  const int c8 = tid & 7;
  const int g8 = c8 ^ (r & 7);

  floatx4 zero4 = {0.f, 0.f, 0.f, 0.f};
  floatx4 acc[4][4];
#pragma unroll
  for (int mt = 0; mt < 4; ++mt)
#pragma unroll
    for (int nt = 0; nt < 4; ++nt) acc[mt][nt] = zero4;

  for (int k0 = 0; k0 < K; k0 += 64) {
    __syncthreads();
#pragma unroll
    for (int p = 0; p < 4; ++p) {
      int row = p * 32 + r;
      load_lds16(A + (size_t)(bm * 128 + row) * K + k0 + g8 * 8, (void*)(As + p * 2048 + wid * 512));
      load_lds16(Bw + (size_t)(bn * 128 + row) * K + k0 + g8 * 8, (void*)(Bs + p * 2048 + wid * 512));
    }
    __syncthreads();
#pragma unroll
    for (int ks = 0; ks < 2; ++ks) {
      const int kk = ks * 4 + q4;
      short8 af[4], bf[4];
#pragma unroll
      for (int mt = 0; mt < 4; ++mt) {
        int row = wm * 64 + mt * 16 + l15;
        af[mt] = *(const short8*)(As + row * 64 + ((kk ^ (row & 7)) << 3));
      }
#pragma unroll
      for (int nt = 0; nt < 4; ++nt) {
        int row = wn * 64 + nt * 16 + l15;
        bf[nt] = *(const short8*)(Bs + row * 64 + ((kk ^ (row & 7)) << 3));
      }
#pragma unroll
      for (int mt = 0; mt < 4; ++mt)
#pragma unroll
        for (int nt = 0; nt < 4; ++nt)
          acc[mt][nt] = __builtin_amdgcn_mfma_f32_16x16x32_bf16(af[mt], bf[nt], acc[mt][nt], 0, 0, 0);
    }
  }

#pragma unroll
  for (int mt = 0; mt < 4; ++mt)
#pragma unroll
    for (int nt = 0; nt < 4; ++nt)
#pragma unroll
      for (int rr = 0; rr < 4; ++rr) {
        int m = bm * 128 + wm * 64 + mt * 16 + q4 * 4 + rr;
        int n = bn * 128 + wn * 64 + nt * 16 + l15;
        float v = acc[mt][nt][rr] + bias[n];
        if (mode == 0) {
          ((ushort_t*)Cout)[(size_t)m * N + n] = f2bf(v);
        } else if (mode == 1) {
          int t = m >> 5, b = m & 31;
          ((float*)Cout)[(size_t)b * (S_LEN * DIN) + t * DIN + n] = v;
        } else {
          int t = m >> 5, b = m & 31;
          ((ushort_t*)Cout)[(size_t)t * (N * 32) + n * 32 + b] = f2bf(v);
        }
      }
}

// ---------------------------------------------------------------------------
// Bidirectional LSTM recurrence — R4 topology/protocol (16 WGs: dir = bx&1,
// j = bx>>1; untagged 64B/thread exchange, epoch-gated), with the serial
// round trips collapsed:
//
//  * MERGED DRAIN: the publish-side vmcnt(0) is no longer a dedicated stall.
//    Order: comm stores -> hout store -> ldxp(tnext) -> unpack xp into regs.
//    The unpack's compiler-emitted vmcnt(0) (vmcnt is in-order) waits for the
//    xp loads, which necessarily drains the older comm/hout store acks for
//    free. A belt-and-braces vm0 before the pre-epoch barrier is then ~0-cost
//    (queue already empty) but preserves the protocol guarantee explicitly.
//
//  * MERGED DETECT+DATA: consumers spec-load their 64B data together with
//    the epoch each spin iteration and accept when epoch >= sc. Freshness:
//    producer separation between data@MALL and epoch@MALL is >= 1 full RT
//    (the drain: epoch store ISSUES only after comm acks returned, i.e.
//    ~2 half-trips after data arrived at MALL), while the consumer's data
//    and epoch MALL accesses are ~tens of cycles apart. On the accept
//    iteration the data reads therefore see post-arrival data regardless of
//    load ordering within the iteration. Steady-state spin count ~1 (the
//    pipeline is latency-matched), so no R1-style bulk-spin traffic storm.
//
//  * Per-thread epoch gating: each thread exits on ITS producer slice's
//    epoch only (no max-over-8 ballot ahead of the data).
//
// Overwrite safety (identical induction to R0/R4, 2-parity double buffer):
// WG A's step-(sc+1) comm stores overwrite buf[sc&1] consumed at step sc.
// A publishes epoch(sc+1) only after (a) its own consume(sc) loads completed
// (their values fed the MFMA earlier in program order) and (b) its comm
// stores reached the coherence point (vmcnt(0) before the pre-epoch
// barrier). Any WG overwrites buf[p] at sc+2 only after observing all
// epochs(sc+1). Graph-replay safe: epochs zeroed per launch; comm data is
// epoch-gated so it needs no init.
// ---------------------------------------------------------------------------
__global__ __launch_bounds__(256) void lstm_layer(
    const ushort_t* __restrict__ xpf, const ushort_t* __restrict__ xpb,
    const ushort_t* __restrict__ whhf, const ushort_t* __restrict__ whhb,
    ushort_t* __restrict__ hout, u64* __restrict__ comm, u64* __restrict__ epochs)
{
  const int bx = blockIdx.x;
  const int dir = bx & 1, j = bx >> 1;

  const ushort_t* xp  = dir ? xpb : xpf;
  const ushort_t* whh = dir ? whhb : whhf;
  u64* commd = comm + (size_t)dir * 4096;  // 2 parities x 2048 u64
  const int hoff = dir * 256;

  __shared__ __align__(16) ushort_t hbuf[32 * 264];  // h_{t-1} bf16, stride 264
  __shared__ __align__(16) float stage[32 * 133];    // gates fp32

  const int tid = threadIdx.x, lane = tid & 63, w = tid >> 6;
  const int l15 = lane & 15, q4 = lane >> 4;

  // permanent B-fragments: wave w owns gate w of slice j (32 gate rows, 2 tiles)
  short8 Bf[2][8];
#pragma unroll
  for (int tl = 0; tl < 2; ++tl) {
    int grow = w * 256 + j * 32 + tl * 16 + l15;
#pragma unroll
    for (int ks = 0; ks < 8; ++ks)
      Bf[tl][ks] = *(const short8*)(whh + (size_t)grow * 256 + ks * 32 + q4 * 8);
  }

  // zero hbuf: h_{-1} = 0 (sc==0 skips the consume phase)
  for (int i = tid; i < 32 * 132; i += 256) ((uint_t*)hbuf)[i] = 0u;

  float cst[4] = {0.f, 0.f, 0.f, 0.f};

  // xp: [t][g][b] layout, one u64 = 4 consecutive batches
  u64 xr64[2][2];
  auto ldxp = [&](int tt) {
#pragma unroll
    for (int mt = 0; mt < 2; ++mt)
#pragma unroll
      for (int tl = 0; tl < 2; ++tl) {
        int g = w * 256 + j * 32 + tl * 16 + l15;
        xr64[mt][tl] = *(const u64*)(xp + (size_t)tt * (GDIM * BATCH) + (size_t)g * 32 + mt * 16 + q4 * 4);
      }
  };
  // persistent unpacked xp for the CURRENT step (filled at prev iteration's
  // drain point, where its vmcnt(0) doubles as the comm-store drain)
  floatx4 xacc[2][2];
  auto unpack_xp = [&]() {
#pragma unroll
    for (int mt = 0; mt < 2; ++mt)
#pragma unroll
      for (int tl = 0; tl < 2; ++tl) {
        u64 v = xr64[mt][tl];
#pragma unroll
        for (int rr = 0; rr < 4; ++rr)
          xacc[mt][tl][rr] = bf2f((ushort_t)(v >> (16 * rr)));
      }
  };

  const int cb  = tid >> 3;      // batch row (producer and consumer)
  const int cg0 = tid & 7;       // consumer col-slice (== producing WG j')
  const int c4  = (tid & 7) * 4; // producer first col (4 consecutive)

  ldxp((dir == 0) ? 0 : 1023);
  unpack_xp();
  __syncthreads();

  for (int sc = 0; sc < 1024; ++sc) {
    const int tcur  = (dir == 0) ? sc : 1023 - sc;
    const int tnext = (dir == 0) ? (sc < 1023 ? sc + 1 : 1023) : (sc < 1023 ? 1022 - sc : 0);

    // ---- consume h_{t-1}: fused spec-load spin (data + epoch, one RT/iter) ----
    if (sc > 0 && cg0 != j) {
      const u64 want = (u64)(unsigned)sc;
      const u64* ea = epochs + ((size_t)(dir * 2 + (sc & 1)) * 8 + cg0) * 16;
      const u64* rbuf = commd + (size_t)(sc & 1) * 2048 + (size_t)cb * 64 + cg0 * 8;
      u64 tmp[8];
      for (;;) {
        // data + epoch issued together; single round trip per iteration.
        // freshness on the accept iteration: see header comment (producer
        // guarantees data@MALL >= 1 RT before epoch@MALL).
#pragma unroll
        for (int k = 0; k < 8; ++k)
          tmp[k] = __hip_atomic_load(rbuf + k, __ATOMIC_RELAXED, __HIP_MEMORY_SCOPE_AGENT);
        u64 ev = __hip_atomic_load(ea, __ATOMIC_RELAXED, __HIP_MEMORY_SCOPE_AGENT);
        if (ev >= want) break;
      }
#pragma unroll
      for (int k = 0; k < 8; ++k)
        *(u64*)(hbuf + cb * 264 + cg0 * 32 + k * 4) = tmp[k];
    }
    lds_barrier();  // hbuf ready; nothing else drained

    // ---- gates = xp + h_{t-1} @ whh^T via MFMA ----
    floatx4 acc[2][2];
#pragma unroll
    for (int mt = 0; mt < 2; ++mt)
#pragma unroll
      for (int tl = 0; tl < 2; ++tl) acc[mt][tl] = xacc[mt][tl];
#pragma unroll
    for (int ks = 0; ks < 8; ++ks) {
      short8 a0 = *(const short8*)(hbuf + l15 * 264 + ks * 32 + q4 * 8);
      short8 a1 = *(const short8*)(hbuf + (16 + l15) * 264 + ks * 32 + q4 * 8);
      acc[0][0] = __builtin_amdgcn_mfma_f32_16x16x32_bf16(a0, Bf[0][ks], acc[0][0], 0, 0, 0);
      acc[0][1] = __builtin_amdgcn_mfma_f32_16x16x32_bf16(a0, Bf[1][ks], acc[0][1], 0, 0, 0);
      acc[1][0] = __builtin_amdgcn_mfma_f32_16x16x32_bf16(a1, Bf[0][ks], acc[1][0], 0, 0, 0);
      acc[1][1] = __builtin_amdgcn_mfma_f32_16x16x32_bf16(a1, Bf[1][ks], acc[1][1], 0, 0, 0);
    }

#pragma unroll
    for (int mt = 0; mt < 2; ++mt)
#pragma unroll
      for (int tl = 0; tl < 2; ++tl)
#pragma unroll
        for (int rr = 0; rr < 4; ++rr)
          stage[(mt * 16 + q4 * 4 + rr) * 133 + w * 32 + tl * 16 + l15] = acc[mt][tl][rr];
    lds_barrier();  // stage ready; still no vm drain

    // ---- elementwise LSTM cell: thread = (batch cb, cols c4..c4+3) ----
    float hv4[4];
#pragma unroll
    for (int i = 0; i < 4; ++i) {
      float gi = stage[cb * 133 +      c4 + i];
      float gf = stage[cb * 133 + 32 + c4 + i];
      float gg = stage[cb * 133 + 64 + c4 + i];
      float go = stage[cb * 133 + 96 + c4 + i];
      float c = sigf(gf) * cst[i] + sigf(gi) * tanh_f(gg);
      cst[i] = c;
      hv4[i] = sigf(go) * tanh_f(c);
    }
    u64 pv = (u64)f2bf(hv4[0]) | ((u64)f2bf(hv4[1]) << 16) |
             ((u64)f2bf(hv4[2]) << 32) | ((u64)f2bf(hv4[3]) << 48);

    // ---- publish: comm+hout stores -> xp prefetch+unpack (its vmcnt(0)
    //      doubles as the comm drain) -> barrier -> epoch ----
    __hip_atomic_store(commd + (size_t)((sc + 1) & 1) * 2048 + (size_t)cb * 64 + j * 8 + (tid & 7),
                       pv, __ATOMIC_RELAXED, __HIP_MEMORY_SCOPE_AGENT);
    *(u64*)(hbuf + cb * 264 + j * 32 + c4) = pv;  // own slice for next step's MFMA
    *(u64*)(hout + (size_t)tcur * (BATCH * 512) + cb * 512 + hoff + j * 32 + c4) = pv;

    ldxp(tnext);   // next step's xp
    unpack_xp();   // forces vmcnt(0): xp RT overlaps comm/hout ack drain

    vm0();  // ~free (queue drained by unpack); explicit protocol guarantee
    __builtin_amdgcn_sched_barrier(0);
    __builtin_amdgcn_s_barrier();
    __builtin_amdgcn_sched_barrier(0);
    if (tid == 0)
      __hip_atomic_store(epochs + ((size_t)(dir * 2 + ((sc + 1) & 1)) * 8 + j) * 16,
                         (u64)(unsigned)(sc + 1), __ATOMIC_RELAXED, __HIP_MEMORY_SCOPE_AGENT);
  }
}

// ---------------------------------------------------------------------------
// Attention scores -> e = exp(s - max_t s), per batch b.
// ---------------------------------------------------------------------------
__global__ __launch_bounds__(256) void attn_scores(
    const ushort_t* __restrict__ h1, const float* __restrict__ attn_w,
    const float* __restrict__ attn_b, float* __restrict__ e_out)
{
  const int b = blockIdx.x;
  __shared__ float sbuf[1024];
  __shared__ float red[4];
  const int tid = threadIdx.x, lane = tid & 63, w = tid >> 6;

  float wreg[8];
#pragma unroll
  for (int i = 0; i < 8; ++i) wreg[i] = attn_w[lane * 8 + i];

  for (int t = w; t < 1024; t += 4) {
    short8 hv = *(const short8*)(h1 + (size_t)t * (BATCH * 512) + b * 512 + lane * 8);
    float dot = 0.f;
#pragma unroll
    for (int i = 0; i < 8; ++i) dot += bf2fs(hv[i]) * wreg[i];
#pragma unroll
    for (int off = 32; off; off >>= 1) dot += __shfl_xor(dot, off);
    if (lane == 0) sbuf[t] = dot + attn_b[0];
  }
  __syncthreads();
  float m = -1e30f;
  for (int t = tid; t < 1024; t += 256) m = fmaxf(m, sbuf[t]);
#pragma unroll
  for (int off = 32; off; off >>= 1) m = fmaxf(m, __shfl_xor(m, off));
  if (lane == 0) red[w] = m;
  __syncthreads();
  float mm = fmaxf(fmaxf(red[0], red[1]), fmaxf(red[2], red[3]));
  for (int t = tid; t < 1024; t += 256) e_out[b * 1024 + t] = __expf(sbuf[t] - mm);
}

// ---------------------------------------------------------------------------
// Cumulative context: ctx[t][b][c] = (sum_{u<=t} e_u h_u[c]) / (sum e_u), bf16.
// ---------------------------------------------------------------------------
__global__ __launch_bounds__(256) void attn_ctx(
    const ushort_t* __restrict__ h1, const float* __restrict__ e_in, ushort_t* __restrict__ ctx)
{
  const int b = blockIdx.x >> 1, half = blockIdx.x & 1;
  const int c = half * 256 + threadIdx.x;
  float num = 0.f, den = 0.f;
  const ushort_t* hp = h1 + b * 512 + c;
  ushort_t* cp = ctx + b * 512 + c;
  const float* ep = e_in + b * 1024;
#pragma unroll 4
  for (int t = 0; t < 1024; ++t) {
    float ev = ep[t];
    float hv = bf2f(hp[(size_t)t * (BATCH * 512)]);
    num += ev * hv;
    den += ev;
    cp[(size_t)t * (BATCH * 512)] = f2bf(num / den);
  }
}

// ---------------------------------------------------------------------------
// casts
// ---------------------------------------------------------------------------
__global__ void castw(const float* __restrict__ in, ushort_t* __restrict__ out, int n) {
  int i = blockIdx.x * 256 + threadIdx.x;
  if (i < n) out[i] = f2bf(in[i]);
}
__global__ void castx(const float* __restrict__ x, ushort_t* __restrict__ xt) {
  int i = blockIdx.x * 256 + threadIdx.x;  // over 32768*128
  int dcol = i & 127;
  int m = i >> 7;
  int b = m & 31, s = m >> 5;
  xt[i] = f2bf(x[(size_t)b * (S_LEN * DIN) + s * DIN + dcol]);
}

extern "C" void kernel_launch(void* const* d_in, const int* in_sizes, int n_in,
                              void* d_out, int out_size, void* d_ws, size_t ws_size,
                              hipStream_t stream)
{
  const float* x     = (const float*)d_in[0];
  const float* wih0f = (const float*)d_in[1];
  const float* whh0f = (const float*)d_in[2];
  const float* b0f   = (const float*)d_in[3];
  const float* wih0b = (const float*)d_in[4];
  const float* whh0b = (const float*)d_in[5];
  const float* b0b   = (const float*)d_in[6];
  const float* wih1f = (const float*)d_in[7];
  const float* whh1f = (const float*)d_in[8];
  const float* b1f   = (const float*)d_in[9];
  const float* wih1b = (const float*)d_in[10];
  const float* whh1b = (const float*)d_in[11];
  const float* b1b   = (const float*)d_in[12];
  const float* attw  = (const float*)d_in[13];
  const float* attb  = (const float*)d_in[14];
  const float* headw = (const float*)d_in[15];
  const float* headb = (const float*)d_in[16];
  float* out = (float*)d_out;

  char* p = (char*)d_ws;
  auto alloc = [&](size_t bytes) {
    char* r = p;
    p += (bytes + 511) & ~(size_t)511;
    return r;
  };
  u64* ep0        = (u64*)alloc(512 * 8);   // layer-0 epochs (2 dir x 2 par x 8 j x 16 u64)
  u64* ep1        = (u64*)alloc(512 * 8);   // layer-1 epochs
  u64* comm0      = (u64*)alloc(8192 * 8);  // layer-0 data: 2 dir x 2 par x 2048 u64
  u64* comm1      = (u64*)alloc(8192 * 8);
  ushort_t* xt    = (ushort_t*)alloc((size_t)32768 * 128 * 2);
  ushort_t* cwih0f = (ushort_t*)alloc(131072 * 2);
  ushort_t* cwih0b = (ushort_t*)alloc(131072 * 2);
  ushort_t* cwhh0f = (ushort_t*)alloc(262144 * 2);
  ushort_t* cwhh0b = (ushort_t*)alloc(262144 * 2);
  ushort_t* cwih1f = (ushort_t*)alloc(524288 * 2);
  ushort_t* cwih1b = (ushort_t*)alloc(524288 * 2);
  ushort_t* cwhh1f = (ushort_t*)alloc(262144 * 2);
  ushort_t* cwhh1b = (ushort_t*)alloc(262144 * 2);
  ushort_t* cwhead = (ushort_t*)alloc(65536 * 2);
  ushort_t* xpA = (ushort_t*)alloc((size_t)32768 * 1024 * 2);
  ushort_t* xpB = (ushort_t*)alloc((size_t)32768 * 1024 * 2);
  ushort_t* h0  = (ushort_t*)alloc((size_t)32768 * 512 * 2);
  ushort_t* h1  = (ushort_t*)alloc((size_t)32768 * 512 * 2);
  float* ebuf   = (float*)alloc(32 * 1024 * 4);
  ushort_t* ctx = xpA;  // reuse (xp dead by then)

  (void)in_sizes; (void)n_in; (void)out_size; (void)ws_size;

  // zero both layers' epoch arrays (data words are epoch-gated; no init needed)
  (void)hipMemsetAsync(ep0, 0, 2 * 512 * 8, stream);

  castw<<<512, 256, 0, stream>>>(wih0f, cwih0f, 131072);
  castw<<<512, 256, 0, stream>>>(wih0b, cwih0b, 131072);
  castw<<<1024, 256, 0, stream>>>(whh0f, cwhh0f, 262144);
  castw<<<1024, 256, 0, stream>>>(whh0b, cwhh0b, 262144);
  castw<<<2048, 256, 0, stream>>>(wih1f, cwih1f, 524288);
  castw<<<2048, 256, 0, stream>>>(wih1b, cwih1b, 524288);
  castw<<<1024, 256, 0, stream>>>(whh1f, cwhh1f, 262144);
  castw<<<1024, 256, 0, stream>>>(whh1b, cwhh1b, 262144);
  castw<<<256, 256, 0, stream>>>(headw, cwhead, 65536);
  castx<<<16384, 256, 0, stream>>>(x, xt);

  // layer 0: xp in transposed [t][g][b] layout (mode 2)
  gemm_bf16<<<dim3(8, 256), 256, 0, stream>>>(xt, cwih0f, b0f, xpA, 32768, 1024, 128, 2);
  gemm_bf16<<<dim3(8, 256), 256, 0, stream>>>(xt, cwih0b, b0b, xpB, 32768, 1024, 128, 2);
  lstm_layer<<<16, 256, 0, stream>>>(xpA, xpB, cwhh0f, cwhh0b, h0, comm0, ep0);

  // layer 1
  gemm_bf16<<<dim3(8, 256), 256, 0, stream>>>(h0, cwih1f, b1f, xpA, 32768, 1024, 512, 2);
  gemm_bf16<<<dim3(8, 256), 256, 0, stream>>>(h0, cwih1b, b1b, xpB, 32768, 1024, 512, 2);
  lstm_layer<<<16, 256, 0, stream>>>(xpA, xpB, cwhh1f, cwhh1b, h1, comm1, ep1);

  // attention + head
  attn_scores<<<32, 256, 0, stream>>>(h1, attw, attb, ebuf);
  attn_ctx<<<64, 256, 0, stream>>>(h1, ebuf, ctx);
  gemm_bf16<<<dim3(1, 256), 256, 0, stream>>>(ctx, cwhead, headb, out, 32768, 128, 512, 1);
}